// Round 1
// baseline (100.690 us; speedup 1.0000x reference)
//
#include <hip/hip_runtime.h>

// Diversity2: mean(0.3 * pearson_corr(softmax(o1/T), softmax(o2/T), axis=1))
// Key identity: corr is invariant to per-row positive scaling + shift, so
// softmax normalization (and max-subtraction) drop out:
//   corr(p1,p2) == corr(exp(o1/T), exp(o2/T))
// Single streaming pass, fp64 accumulation (covariance formula cancels
// ~1000-magnitude sums to ~0.08; fp32 would lose ~5%, fp64 loses ~1e-10).

#define N_ROWS 65536
#define N_C    1000
#define N_C4   250          // float4 per row; row stride 4000 B is 16B-aligned
#define S1_BLOCKS 2048      // 256 CU * 8 blocks
#define WAVES_PER_BLOCK 4

__device__ __forceinline__ double wave_reduce_add(double v) {
    #pragma unroll
    for (int off = 32; off > 0; off >>= 1)
        v += __shfl_down(v, off, 64);
    return v;   // valid in lane 0
}

__global__ __launch_bounds__(256) void div2_stage1(
        const float* __restrict__ o1, const float* __restrict__ o2,
        double* __restrict__ ws) {
    const int wave = threadIdx.x >> 6;
    const int lane = threadIdx.x & 63;
    const int gwave = blockIdx.x * WAVES_PER_BLOCK + wave;
    const int nwaves = gridDim.x * WAVES_PER_BLOCK;

    constexpr float INV_T = 1.0f / 20.0f;
    double acc = 0.0;  // sum of per-row costs handled by this wave (lane 0 only)

    for (int row = gwave; row < N_ROWS; row += nwaves) {
        const float4* r1 = reinterpret_cast<const float4*>(o1 + (size_t)row * N_C);
        const float4* r2 = reinterpret_cast<const float4*>(o2 + (size_t)row * N_C);
        double sx = 0.0, sy = 0.0, sxx = 0.0, syy = 0.0, sxy = 0.0;
        for (int j = lane; j < N_C4; j += 64) {
            float4 a = r1[j];
            float4 b = r2[j];
            #pragma unroll
            for (int k = 0; k < 4; ++k) {
                float av = (k == 0) ? a.x : (k == 1) ? a.y : (k == 2) ? a.z : a.w;
                float bv = (k == 0) ? b.x : (k == 1) ? b.y : (k == 2) ? b.z : b.w;
                float xf = __expf(av * INV_T);
                float yf = __expf(bv * INV_T);
                double x = (double)xf, y = (double)yf;
                sx += x;  sy += y;
                sxx = fma(x, x, sxx);
                syy = fma(y, y, syy);
                sxy = fma(x, y, sxy);
            }
        }
        sx  = wave_reduce_add(sx);
        sy  = wave_reduce_add(sy);
        sxx = wave_reduce_add(sxx);
        syy = wave_reduce_add(syy);
        sxy = wave_reduce_add(sxy);
        if (lane == 0) {
            constexpr double invC = 1.0 / (double)N_C;
            double num = sxy - sx * sy * invC;
            double vx  = sxx - sx * sx * invC;
            double vy  = syy - sy * sy * invC;
            acc += num / sqrt(vx * vy);
        }
    }

    __shared__ double lds[WAVES_PER_BLOCK];
    if (lane == 0) lds[wave] = acc;
    __syncthreads();
    if (threadIdx.x == 0) {
        double s = 0.0;
        #pragma unroll
        for (int w = 0; w < WAVES_PER_BLOCK; ++w) s += lds[w];
        ws[blockIdx.x] = s;
    }
}

__global__ __launch_bounds__(256) void div2_stage2(
        const double* __restrict__ ws, int n, float* __restrict__ out) {
    double s = 0.0;
    for (int i = threadIdx.x; i < n; i += 256) s += ws[i];
    s = wave_reduce_add(s);
    __shared__ double lds[4];
    const int wave = threadIdx.x >> 6;
    const int lane = threadIdx.x & 63;
    if (lane == 0) lds[wave] = s;
    __syncthreads();
    if (threadIdx.x == 0) {
        double t = lds[0] + lds[1] + lds[2] + lds[3];
        out[0] = (float)(t * (0.3 / (double)N_ROWS));
    }
}

extern "C" void kernel_launch(void* const* d_in, const int* in_sizes, int n_in,
                              void* d_out, int out_size, void* d_ws, size_t ws_size,
                              hipStream_t stream) {
    const float* o1 = (const float*)d_in[0];
    const float* o2 = (const float*)d_in[1];
    // d_in[2] (targets) is unused by the reference.
    float* out = (float*)d_out;
    double* ws = (double*)d_ws;

    int nblocks = S1_BLOCKS;
    size_t need = (size_t)nblocks * sizeof(double);
    if (ws_size < need) {
        nblocks = (int)(ws_size / sizeof(double));
        if (nblocks < 1) nblocks = 1;
    }

    div2_stage1<<<nblocks, 256, 0, stream>>>(o1, o2, ws);
    div2_stage2<<<1, 256, 0, stream>>>(ws, nblocks, out);
}